// Round 13
// baseline (257.943 us; speedup 1.0000x reference)
//
#include <hip/hip_runtime.h>
#include <math.h>

#define T_STEPS 256
#define BATCH   2048
#define HID     10

#define S2P  2.8853900817779268f   // 2/ln2
#define SNP -1.4426950408889634f   // -1/ln2
#define LN2  0.6931471805599453f
#define LOGPI 1.1447298858494002f

__device__ __forceinline__ float frcp(float x){ return __builtin_amdgcn_rcpf(x); }
__device__ __forceinline__ float ex2 (float x){ return __builtin_amdgcn_exp2f(x); }
__device__ __forceinline__ float ftanh2(float y){ return 1.f - 2.f*frcp(1.f + ex2(y)); }
__device__ __forceinline__ float fsigm2(float y){ return frcp(1.f + ex2(y)); }

template<int K> __device__ __forceinline__ float rotk(float x){
  return __int_as_float(__builtin_amdgcn_update_dpp(
      0, __float_as_int(x), 0x120 + K, 0xF, 0xF, false));
}
#define ROT16(r, v) do{ float _v=(v); r[0]=_v; \
  r[1]=rotk<1>(_v);  r[2]=rotk<2>(_v);  r[3]=rotk<3>(_v);  r[4]=rotk<4>(_v);  \
  r[5]=rotk<5>(_v);  r[6]=rotk<6>(_v);  r[7]=rotk<7>(_v);  r[8]=rotk<8>(_v);  \
  r[9]=rotk<9>(_v);  r[10]=rotk<10>(_v);r[11]=rotk<11>(_v);r[12]=rotk<12>(_v);\
  r[13]=rotk<13>(_v);r[14]=rotk<14>(_v);r[15]=rotk<15>(_v); }while(0)

__device__ __forceinline__ float dot16(const float* r, const float* w, float bias){
  float a0 = fmaf(r[0], w[0], bias);
  float a1 = r[1]*w[1];
  float a2 = r[2]*w[2];
  float a3 = r[3]*w[3];
  #pragma unroll
  for (int k=4;k<16;k+=4){
    a0 = fmaf(r[k  ], w[k  ], a0);
    a1 = fmaf(r[k+1], w[k+1], a1);
    a2 = fmaf(r[k+2], w[k+2], a2);
    a3 = fmaf(r[k+3], w[k+3], a3);
  }
  return (a0+a1)+(a2+a3);
}

template<int NROW, int NCOL>
__device__ __forceinline__ void loadrot(float* dst, const float* W, int j, int col,
                                        bool colok, float scale){
  int colc = colok ? col : 0;
  #pragma unroll
  for (int k=0;k<16;k++){
    int i = (j - k) & 15;
    bool v = colok && (i < NROW);
    int ic = v ? i : 0;
    float w = W[ic*NCOL + colc];
    dst[k] = v ? scale*w : 0.f;
  }
}
__device__ __forceinline__ float bload(const float* p, int idx, bool ok, float scale){
  float t = p[ok ? idx : 0];
  return ok ? scale*t : 0.f;
}
template<int X> __device__ __forceinline__ float xor16(float x){
  return __int_as_float(__builtin_amdgcn_ds_swizzle(__float_as_int(x), (X<<10)|0x1f));
}

struct P34 { const float* p[34]; float* out; };

// 3 waves/block, 4 chains/block, one barrier per step.
// wave0: serial inference chain only        (z,q -> LDS)
// wave1: e-stage (ae) + transition prior + KLD
// wave2: generator + GLL + generation stores
__global__ __attribute__((amdgpu_flat_work_group_size(192, 192), amdgpu_waves_per_eu(1, 1)))
void k_fused(P34 prm)
{
  __shared__ float zb [4][64];    // z ring (slot = s & 3)
  __shared__ float qmB[2][64];    // q_mu (slot = s & 1)
  __shared__ float qsB[2][64];    // q_sg
  __shared__ float aeB[2][64];    // ae   (slot = t & 1)
  __shared__ float part[3][4];    // per-wave loss partials per chain group

  const int tx   = threadIdx.x;
  const int wid  = tx / 64;
  const int lane = tx & 63;
  const int j    = lane & 15;
  const int grp  = lane >> 4;
  const int b    = blockIdx.x*4 + grp;
  const bool act = (j < HID);
  const int  jl  = act ? j : 0;

  const float* __restrict__ seq   = prm.p[0];
  const float* __restrict__ noise = prm.p[1];
  float* __restrict__ out = prm.out;

  float LL = 0.f, L2 = 0.f;

  if (wid == 0){
    // =============== wave 0: serial chain ===============
    float w_jz[16]; loadrot<10,10>(w_jz, prm.p[12] + 100, j, j, act, S2P);
    float w_h [16]; loadrot<10,10>(w_h,  prm.p[14],       j, j, act, S2P);
    float wmu [16]; loadrot<10,10>(wmu,  prm.p[16],       j, j, act, S2P);
    float wsg [16]; loadrot<10,10>(wsg,  prm.p[18],       j, j, act, SNP);
    float b_in_h  = bload(prm.p[15], jl, act, S2P);
    float b_mu    = bload(prm.p[17], jl, act, S2P);
    float b_sg    = bload(prm.p[19], jl, act, SNP);

    auto lde = [&](int t){ return noise[t*BATCH*HID + b*HID + jl]; };

    float z_prev;
    { // t=0: first_inference + KL vs unit prior
      float w0 = bload(prm.p[2],      jl, act, S2P);
      float w1 = bload(prm.p[2], 10 + jl, act, S2P);
      float bb = bload(prm.p[3], jl, act, S2P);
      float f_h[16], f_mu[16], f_sg[16];
      loadrot<10,10>(f_h,  prm.p[4], j, j, act, S2P);  float fb_h  = bload(prm.p[5], jl, act, S2P);
      loadrot<10,10>(f_mu, prm.p[6], j, j, act, S2P);  float fb_mu = bload(prm.p[7], jl, act, S2P);
      loadrot<10,10>(f_sg, prm.p[8], j, j, act, SNP);  float fb_sg = bload(prm.p[9], jl, act, SNP);
      float2 x0 = *reinterpret_cast<const float2*>(seq + b*2);
      float eps = lde(0);
      float h0 = ftanh2(fmaf(x0.x, w0, fmaf(x0.y, w1, bb)));
      float r0[16]; ROT16(r0, h0);
      float h1 = ftanh2(dot16(r0, f_h, fb_h));
      float r1[16]; ROT16(r1, h1);
      float mu = ftanh2(dot16(r1, f_mu, fb_mu));
      float sg = fsigm2(dot16(r1, f_sg, fb_sg)) + 0.001f;
      if (act){ LL += sg + mu*mu; L2 -= __log2f(sg); }
      z_prev = fmaf(sg, eps, mu);
      zb[0][lane] = z_prev;
    }
    float e0=lde(1), e1=lde(2), e2=lde(3), e3=lde(4);
    __syncthreads();                                    // prologue barrier

    for (int s = 1; s <= 256; ++s){
      if (s <= 255){
        int tn = s + 4; if (tn > 255) tn = 255;
        float en = lde(tn);
        float aev = aeB[s&1][lane];
        float rz[16]; ROT16(rz, z_prev);
        float hj = ftanh2(aev + dot16(rz, w_jz, 0.f));
        float rhj[16]; ROT16(rhj, hj);
        float hi = ftanh2(dot16(rhj, w_h, b_in_h));
        float rhi[16]; ROT16(rhi, hi);
        float q_mu = ftanh2(dot16(rhi, wmu, b_mu));
        float q_sg = fsigm2(dot16(rhi, wsg, b_sg)) + 0.001f;
        float z = fmaf(q_sg, e0, q_mu);
        zb [s&3][lane] = z;
        qmB[s&1][lane] = q_mu;
        qsB[s&1][lane] = q_sg;
        z_prev = z;
        e0=e1; e1=e2; e2=e3; e3=en;
      }
      __syncthreads();
    }
  } else if (wid == 1){
    // =============== wave 1: e-stage + prior + KLD ===============
    float w_ii0   = bload(prm.p[10],      jl, act, S2P);
    float w_ii1   = bload(prm.p[10], 10 + jl, act, S2P);
    float b_in_in = bload(prm.p[11], jl, act, S2P);
    float w_je[16]; loadrot<10,10>(w_je, prm.p[12], j, j, act, S2P);
    float b_in_j  = bload(prm.p[13], jl, act, S2P);

    float wth [16]; loadrot<10,10>(wth,  prm.p[20], j, j, act, S2P);
    float bth  = bload(prm.p[21], jl, act, S2P);
    float wtmu[16]; loadrot<10,10>(wtmu, prm.p[22], j, j, act, S2P);
    float btmu = bload(prm.p[23], jl, act, S2P);
    float wtsg[16]; loadrot<10,10>(wtsg, prm.p[24], j, j, act, S2P);
    float btsg = bload(prm.p[25], jl, act, S2P);

    auto ldx = [&](int t){ return *reinterpret_cast<const float2*>(seq + t*BATCH*2 + b*2); };

    { // prologue: ae(1) from x(1)
      float2 x1 = ldx(1);
      float e = ftanh2(fmaf(x1.x, w_ii0, fmaf(x1.y, w_ii1, b_in_in)));
      float re[16]; ROT16(re, e);
      aeB[1][lane] = dot16(re, w_je, b_in_j);
    }
    float2 xq0 = ldx(2), xq1 = ldx(3);                  // x(s+1), x(s+2)
    __syncthreads();                                    // prologue barrier

    for (int s = 1; s <= 256; ++s){
      if (s <= 254){                                    // ae(s+1) from x(s+1)
        int tn = s + 3; if (tn > 255) tn = 255;
        float2 xn = ldx(tn);
        float e = ftanh2(fmaf(xq0.x, w_ii0, fmaf(xq0.y, w_ii1, b_in_in)));
        float re[16]; ROT16(re, e);
        aeB[(s+1)&1][lane] = dot16(re, w_je, b_in_j);
        xq0 = xq1; xq1 = xn;
      }
      if (s >= 2){                                      // KLD(t=s-1): prior(z(s-2)), q(s-1)
        float zp  = zb [(s-2)&3][lane];
        float qmu = qmB[(s-1)&1][lane];
        float qsg = qsB[(s-1)&1][lane];
        float rz[16]; ROT16(rz, zp);
        float th = ftanh2(dot16(rz, wth, bth));
        float rth[16]; ROT16(rth, th);
        float prmu = ftanh2(dot16(rth, wtmu, btmu));
        float prsg = ftanh2(dot16(rth, wtsg, btsg));
        if (act){
          float dmu = prmu - qmu;
          float rp  = frcp(prsg);
          LL += (qsg + dmu*dmu)*rp;
          L2 += __log2f(prsg) - __log2f(qsg);
        }
      }
      __syncthreads();
    }
  } else {
    // =============== wave 2: generator + GLL ===============
    float wg1[16]; loadrot<10,10>(wg1, prm.p[26], j, j, act, 1.f);
    float bg1 = bload(prm.p[27], jl, act, 1.f);
    float wg2[16]; loadrot<10,10>(wg2, prm.p[28], j, j, act, 1.f);
    float bg2 = bload(prm.p[29], jl, act, 1.f);
    const bool isd = (j < 4);
    const float* Wgo = (j < 2) ? prm.p[30] : prm.p[32];
    const float* Bgo = (j < 2) ? prm.p[31] : prm.p[33];
    float wgo[16]; loadrot<10,2>(wgo, Wgo, j, j & 1, isd, SNP);
    float bgo = bload(Bgo, j & 1, isd, SNP);

    auto ldx = [&](int t){ return *reinterpret_cast<const float2*>(seq + t*BATCH*2 + b*2); };
    float2 xg = ldx(0), xg1 = ldx(1);                   // x(s-1), x(s)
    __syncthreads();                                    // prologue barrier

    for (int s = 1; s <= 256; ++s){
      int tn = s + 1; if (tn > 255) tn = 255;
      float2 xn = ldx(tn);
      float zl = zb[(s-1)&3][lane];                     // z(s-1)
      float rz[16]; ROT16(rz, zl);
      float g1 = fmaxf(dot16(rz, wg1, bg1), 0.f);
      float rg1[16]; ROT16(rg1, g1);
      float g2 = fmaxf(dot16(rg1, wg2, bg2), 0.f);
      float rg2[16]; ROT16(rg2, g2);
      float ygo = dot16(rg2, wgo, bgo);
      float tgo = 1.f + ex2(ygo);                       // 1/sigmoid
      float tpl = rotk<14>(tgo);                        // lanes 0,1 <- 2,3
      if (j < 2){
        float m = frcp(tgo);
        out[(s-1)*(BATCH*2) + b*2 + j] = m;
        float dd = ((j==0) ? xg.x : xg.y) - m;
        LL -= dd*dd*tpl;
        L2 += __log2f(tpl);
      }
      xg = xg1; xg1 = xn;
      __syncthreads();
    }
  }

  // combine per-wave loss partials
  float tot = fmaf(LN2, L2, LL);
  tot += xor16<1>(tot); tot += xor16<2>(tot); tot += xor16<4>(tot); tot += xor16<8>(tot);
  if (j == 0) part[wid][grp] = tot;
  __syncthreads();
  if (wid == 0 && j == 0)
    out[T_STEPS*BATCH*2 + b] =
      -(part[0][grp] + part[1][grp] + part[2][grp])*(1.0f/512.0f) + 5.0f + LOGPI;
}

extern "C" void kernel_launch(void* const* d_in, const int* in_sizes, int n_in,
                              void* d_out, int out_size, void* d_ws, size_t ws_size,
                              hipStream_t stream) {
  P34 prm;
  for (int i = 0; i < 34; ++i) prm.p[i] = (const float*)d_in[i];
  prm.out = (float*)d_out;
  hipLaunchKernelGGL(k_fused, dim3(512), dim3(192), 0, stream, prm);
}

// Round 14
// 167.830 us; speedup vs baseline: 1.5369x; 1.5369x over previous
//
#include <hip/hip_runtime.h>
#include <math.h>

#define T_STEPS 256
#define BATCH   2048
#define HID     10

#define S2P  2.8853900817779268f   // 2/ln2
#define SNP -1.4426950408889634f   // -1/ln2
#define LN2  0.6931471805599453f
#define LOGPI 1.1447298858494002f

__device__ __forceinline__ float frcp(float x){ return __builtin_amdgcn_rcpf(x); }
__device__ __forceinline__ float ex2 (float x){ return __builtin_amdgcn_exp2f(x); }
__device__ __forceinline__ float ftanh2(float y){ return 1.f - 2.f*frcp(1.f + ex2(y)); }
__device__ __forceinline__ float fsigm2(float y){ return frcp(1.f + ex2(y)); }

template<int K> __device__ __forceinline__ float rotk(float x){
  return __int_as_float(__builtin_amdgcn_update_dpp(
      0, __float_as_int(x), 0x120 + K, 0xF, 0xF, false));
}
#define ROT16(r, v) do{ float _v=(v); r[0]=_v; \
  r[1]=rotk<1>(_v);  r[2]=rotk<2>(_v);  r[3]=rotk<3>(_v);  r[4]=rotk<4>(_v);  \
  r[5]=rotk<5>(_v);  r[6]=rotk<6>(_v);  r[7]=rotk<7>(_v);  r[8]=rotk<8>(_v);  \
  r[9]=rotk<9>(_v);  r[10]=rotk<10>(_v);r[11]=rotk<11>(_v);r[12]=rotk<12>(_v);\
  r[13]=rotk<13>(_v);r[14]=rotk<14>(_v);r[15]=rotk<15>(_v); }while(0)

__device__ __forceinline__ float dot16(const float* r, const float* w, float bias){
  float a0 = fmaf(r[0], w[0], bias);
  float a1 = r[1]*w[1];
  float a2 = r[2]*w[2];
  float a3 = r[3]*w[3];
  #pragma unroll
  for (int k=4;k<16;k+=4){
    a0 = fmaf(r[k  ], w[k  ], a0);
    a1 = fmaf(r[k+1], w[k+1], a1);
    a2 = fmaf(r[k+2], w[k+2], a2);
    a3 = fmaf(r[k+3], w[k+3], a3);
  }
  return (a0+a1)+(a2+a3);
}

template<int NROW, int NCOL>
__device__ __forceinline__ void loadrot(float* dst, const float* W, int j, int col,
                                        bool colok, float scale){
  int colc = colok ? col : 0;
  #pragma unroll
  for (int k=0;k<16;k++){
    int i = (j - k) & 15;
    bool v = colok && (i < NROW);
    int ic = v ? i : 0;
    float w = W[ic*NCOL + colc];
    dst[k] = v ? scale*w : 0.f;
  }
}
__device__ __forceinline__ float bload(const float* p, int idx, bool ok, float scale){
  float t = p[ok ? idx : 0];
  return ok ? scale*t : 0.f;
}
template<int X> __device__ __forceinline__ float xor16(float x){
  return __int_as_float(__builtin_amdgcn_ds_swizzle(__float_as_int(x), (X<<10)|0x1f));
}

struct P34 { const float* p[34]; float* out; };

// 2 waves/block (128 thr), 4 chains/block -> 1024 waves = exactly 1/SIMD.
// wave0: serial chain + th (transition hidden) + g1 (gen layer 1)   [all reuse rot(z)]
// wave1: e-stage + prior heads + KLD + gen layers 2/head + GLL + stores
// g1(t) written at step t+1, consumed at step t+2 (2-step gen lag). All parity
// slots: wave0 writes th/q[s&1], g1[(s-1)&1]; wave1 reads th/q[(s-1)&1], g1[(s-2)&1].
__global__ __attribute__((amdgpu_flat_work_group_size(128, 128), amdgpu_waves_per_eu(1, 1)))
void k_fused(P34 prm)
{
  __shared__ float aeB[2][64], thB[2][64], qmB[2][64], qsB[2][64], g1B[2][64];
  __shared__ float part[2][4];

  const int tx   = threadIdx.x;
  const int wid  = tx >> 6;
  const int lane = tx & 63;
  const int j    = lane & 15;
  const int grp  = lane >> 4;
  const int b    = blockIdx.x*4 + grp;
  const bool act = (j < HID);
  const int  jl  = act ? j : 0;

  const float* __restrict__ seq   = prm.p[0];
  const float* __restrict__ noise = prm.p[1];
  float* __restrict__ out = prm.out;

  float LL = 0.f, L2 = 0.f;

  if (wid == 0){
    // =============== wave 0 ===============
    float w_jz[16]; loadrot<10,10>(w_jz, prm.p[12] + 100, j, j, act, S2P);
    float w_h [16]; loadrot<10,10>(w_h,  prm.p[14],       j, j, act, S2P);
    float wmu [16]; loadrot<10,10>(wmu,  prm.p[16],       j, j, act, S2P);
    float wsg [16]; loadrot<10,10>(wsg,  prm.p[18],       j, j, act, SNP);
    float wth [16]; loadrot<10,10>(wth,  prm.p[20],       j, j, act, S2P);
    float wg1 [16]; loadrot<10,10>(wg1,  prm.p[26],       j, j, act, 1.f);
    float b_in_h = bload(prm.p[15], jl, act, S2P);
    float b_mu   = bload(prm.p[17], jl, act, S2P);
    float b_sg   = bload(prm.p[19], jl, act, SNP);
    float bth    = bload(prm.p[21], jl, act, S2P);
    float bg1    = bload(prm.p[27], jl, act, 1.f);

    auto lde = [&](int t){ return noise[t*BATCH*HID + b*HID + jl]; };

    float z_prev;
    { // t=0: first_inference + KL vs unit prior
      float w0 = bload(prm.p[2],      jl, act, S2P);
      float w1 = bload(prm.p[2], 10 + jl, act, S2P);
      float bb = bload(prm.p[3], jl, act, S2P);
      float f_h[16], f_mu[16], f_sg[16];
      loadrot<10,10>(f_h,  prm.p[4], j, j, act, S2P);  float fb_h  = bload(prm.p[5], jl, act, S2P);
      loadrot<10,10>(f_mu, prm.p[6], j, j, act, S2P);  float fb_mu = bload(prm.p[7], jl, act, S2P);
      loadrot<10,10>(f_sg, prm.p[8], j, j, act, SNP);  float fb_sg = bload(prm.p[9], jl, act, SNP);
      float2 x0 = *reinterpret_cast<const float2*>(seq + b*2);
      float eps = lde(0);
      float h0 = ftanh2(fmaf(x0.x, w0, fmaf(x0.y, w1, bb)));
      float r0[16]; ROT16(r0, h0);
      float h1 = ftanh2(dot16(r0, f_h, fb_h));
      float r1[16]; ROT16(r1, h1);
      float mu = ftanh2(dot16(r1, f_mu, fb_mu));
      float sg = fsigm2(dot16(r1, f_sg, fb_sg)) + 0.001f;
      if (act){ LL += sg + mu*mu; L2 -= __log2f(sg); }
      z_prev = fmaf(sg, eps, mu);
    }
    float e0=lde(1), e1=lde(2), e2=lde(3), e3=lde(4);
    __syncthreads();                                   // prologue barrier

    // full step (s = 1..255): chain + th + g1, all off rot(z_prev)
    auto w0step = [&](int AE, int TQ, int G1, float ec){
      float aev = aeB[AE][lane];
      float rz[16]; ROT16(rz, z_prev);
      float hj = ftanh2(aev + dot16(rz, w_jz, 0.f));
      float th = ftanh2(dot16(rz, wth, bth));
      float g1 = fmaxf(dot16(rz, wg1, bg1), 0.f);
      thB[TQ][lane] = th;
      g1B[G1][lane] = g1;
      float rhj[16]; ROT16(rhj, hj);
      float hi = ftanh2(dot16(rhj, w_h, b_in_h));
      float rhi[16]; ROT16(rhi, hi);
      float q_mu = ftanh2(dot16(rhi, wmu, b_mu));
      float q_sg = fsigm2(dot16(rhi, wsg, b_sg)) + 0.001f;
      qmB[TQ][lane] = q_mu;
      qsB[TQ][lane] = q_sg;
      z_prev = fmaf(q_sg, ec, q_mu);
    };

    for (int p = 0; p < 125; ++p){                     // s = 2p+1, 2p+2  (1..250)
      int s = 2*p + 1;
      float n0 = lde(s+4), n1 = lde(s+5);
      w0step(1, 1, 0, e0); __syncthreads();            // s odd
      w0step(0, 0, 1, e1); __syncthreads();            // s even
      e0=e2; e1=e3; e2=n0; e3=n1;
    }
    float e255 = lde(255);                             // queue: e0..e3 = eps(251..254)
    w0step(1, 1, 0, e0);   __syncthreads();            // 251
    w0step(0, 0, 1, e1);   __syncthreads();            // 252
    w0step(1, 1, 0, e2);   __syncthreads();            // 253
    w0step(0, 0, 1, e3);   __syncthreads();            // 254
    w0step(1, 1, 0, e255); __syncthreads();            // 255
    { // s=256: only g1(255) from z(255)
      float rz[16]; ROT16(rz, z_prev);
      g1B[1][lane] = fmaxf(dot16(rz, wg1, bg1), 0.f);
    }
    __syncthreads();                                   // 256
    __syncthreads();                                   // 257 (idle)
  } else {
    // =============== wave 1 ===============
    float w_ii0   = bload(prm.p[10],      jl, act, S2P);
    float w_ii1   = bload(prm.p[10], 10 + jl, act, S2P);
    float b_in_in = bload(prm.p[11], jl, act, S2P);
    float w_je[16]; loadrot<10,10>(w_je, prm.p[12], j, j, act, S2P);
    float b_in_j  = bload(prm.p[13], jl, act, S2P);

    float wtmu[16]; loadrot<10,10>(wtmu, prm.p[22], j, j, act, S2P);
    float btmu = bload(prm.p[23], jl, act, S2P);
    float wtsg[16]; loadrot<10,10>(wtsg, prm.p[24], j, j, act, S2P);
    float btsg = bload(prm.p[25], jl, act, S2P);

    float wg2[16]; loadrot<10,10>(wg2, prm.p[28], j, j, act, 1.f);
    float bg2 = bload(prm.p[29], jl, act, 1.f);
    const bool isd = (j < 4);
    const float* Wgo = (j < 2) ? prm.p[30] : prm.p[32];
    const float* Bgo = (j < 2) ? prm.p[31] : prm.p[33];
    float wgo[16]; loadrot<10,2>(wgo, Wgo, j, j & 1, isd, SNP);
    float bgo = bload(Bgo, j & 1, isd, SNP);

    auto ldx = [&](int t){ return *reinterpret_cast<const float2*>(seq + t*BATCH*2 + b*2); };
    const float* xgp = seq + b*2;                      // walks x(0),x(1),... for GLL

    auto estage = [&](float2 xe, int AW){
      float e = ftanh2(fmaf(xe.x, w_ii0, fmaf(xe.y, w_ii1, b_in_in)));
      float re[16]; ROT16(re, e);
      aeB[AW][lane] = dot16(re, w_je, b_in_j);
    };
    // gen(t = s-2) from g1B[G1]; GLL vs x(t) loaded via xgp; store out[t]
    auto genstep = [&](int G1, int tG){
      float2 xg = *reinterpret_cast<const float2*>(xgp);
      float g1 = g1B[G1][lane];
      float rg1[16]; ROT16(rg1, g1);
      float g2 = fmaxf(dot16(rg1, wg2, bg2), 0.f);
      float rg2[16]; ROT16(rg2, g2);
      float ygo = dot16(rg2, wgo, bgo);
      float tgo = 1.f + ex2(ygo);                      // 1/sigmoid
      float tpl = rotk<14>(tgo);                       // lanes 0,1 <- 2,3
      if (j < 2){
        float m = frcp(tgo);
        out[tG*(BATCH*2) + b*2 + j] = m;
        float dd = ((j==0) ? xg.x : xg.y) - m;
        LL -= dd*dd*tpl;
        L2 += __log2f(tpl);
      }
      xgp += BATCH*2;
    };
    // KLD(t = s-1): th,q from slot TQ
    auto klstep = [&](int TQ){
      float th = thB[TQ][lane];
      float qm = qmB[TQ][lane];
      float qs = qsB[TQ][lane];
      float rth[16]; ROT16(rth, th);
      float prmu = ftanh2(dot16(rth, wtmu, btmu));
      float prsg = ftanh2(dot16(rth, wtsg, btsg));
      if (act){
        float dmu = prmu - qm;
        float rp  = frcp(prsg);
        LL += (qs + dmu*dmu)*rp;
        L2 += __log2f(prsg) - __log2f(qs);
      }
    };

    { // prologue: ae(1) from x(1)
      float2 x1 = ldx(1);
      estage(x1, 1);
    }
    float2 xq0 = ldx(2), xq1 = ldx(3), xq2 = ldx(4), xq3 = ldx(5);
    __syncthreads();                                   // prologue barrier

    // s=1: e only
    { float2 xn = ldx(6); estage(xq0, 0); xq0=xq1; xq1=xq2; xq2=xq3; xq3=xn; }
    __syncthreads();
    // s=2: e + gen(0) + KLD(1)
    { float2 xn = ldx(7); estage(xq0, 1); genstep(0, 0); klstep(1);
      xq0=xq1; xq1=xq2; xq2=xq3; xq3=xn; }
    __syncthreads();

    for (int p = 1; p < 125; ++p){                     // s = 2p+1, 2p+2  (3..250)
      int s = 2*p + 1;
      float2 n0 = ldx(s+5), n1 = ldx(s+6);
      estage(xq0, 0); genstep(1, s-2); klstep(0); __syncthreads();   // s odd
      estage(xq1, 1); genstep(0, s-1); klstep(1); __syncthreads();   // s even
      xq0=xq2; xq1=xq3; xq2=n0; xq3=n1;
    }
    // queue: xq0..xq3 = x(252..255)
    estage(xq0, 0); genstep(1, 249); klstep(0); __syncthreads();     // 251
    estage(xq1, 1); genstep(0, 250); klstep(1); __syncthreads();     // 252
    estage(xq2, 0); genstep(1, 251); klstep(0); __syncthreads();     // 253
    estage(xq3, 1); genstep(0, 252); klstep(1); __syncthreads();     // 254
    genstep(1, 253); klstep(0); __syncthreads();                     // 255
    genstep(0, 254); klstep(1); __syncthreads();                     // 256
    genstep(1, 255);            __syncthreads();                     // 257
  }

  // combine per-wave loss partials
  float tot = fmaf(LN2, L2, LL);
  tot += xor16<1>(tot); tot += xor16<2>(tot); tot += xor16<4>(tot); tot += xor16<8>(tot);
  if (j == 0) part[wid][grp] = tot;
  __syncthreads();
  if (wid == 0 && j == 0)
    out[T_STEPS*BATCH*2 + b] =
      -(part[0][grp] + part[1][grp])*(1.0f/512.0f) + 5.0f + LOGPI;
}

extern "C" void kernel_launch(void* const* d_in, const int* in_sizes, int n_in,
                              void* d_out, int out_size, void* d_ws, size_t ws_size,
                              hipStream_t stream) {
  P34 prm;
  for (int i = 0; i < 34; ++i) prm.p[i] = (const float*)d_in[i];
  prm.out = (float*)d_out;
  hipLaunchKernelGGL(k_fused, dim3(512), dim3(128), 0, stream, prm);
}

// Round 15
// 142.331 us; speedup vs baseline: 1.8123x; 1.1792x over previous
//
#include <hip/hip_runtime.h>
#include <math.h>

#define T_STEPS 256
#define BATCH   2048
#define HID     10

#define S2P  2.8853900817779268f   // 2/ln2
#define SNP -1.4426950408889634f   // -1/ln2
#define LN2  0.6931471805599453f
#define LOGPI 1.1447298858494002f

typedef float v2f __attribute__((ext_vector_type(2)));

__device__ __forceinline__ float frcp(float x){ return __builtin_amdgcn_rcpf(x); }
__device__ __forceinline__ float ex2 (float x){ return __builtin_amdgcn_exp2f(x); }
__device__ __forceinline__ float ftanh2(float y){ return 1.f - 2.f*frcp(1.f + ex2(y)); }
__device__ __forceinline__ float fsigm2(float y){ return frcp(1.f + ex2(y)); }

template<int K> __device__ __forceinline__ float rotk(float x){
  return __int_as_float(__builtin_amdgcn_update_dpp(
      0, __float_as_int(x), 0x120 + K, 0xF, 0xF, false));
}
#define ROT16(r, v) do{ float _v=(v); r[0]=_v; \
  r[1]=rotk<1>(_v);  r[2]=rotk<2>(_v);  r[3]=rotk<3>(_v);  r[4]=rotk<4>(_v);  \
  r[5]=rotk<5>(_v);  r[6]=rotk<6>(_v);  r[7]=rotk<7>(_v);  r[8]=rotk<8>(_v);  \
  r[9]=rotk<9>(_v);  r[10]=rotk<10>(_v);r[11]=rotk<11>(_v);r[12]=rotk<12>(_v);\
  r[13]=rotk<13>(_v);r[14]=rotk<14>(_v);r[15]=rotk<15>(_v); }while(0)

__device__ __forceinline__ float dot16(const float* r, const float* w, float bias){
  float a0 = fmaf(r[0], w[0], bias);
  float a1 = r[1]*w[1];
  float a2 = r[2]*w[2];
  float a3 = r[3]*w[3];
  #pragma unroll
  for (int k=4;k<16;k+=4){
    a0 = fmaf(r[k  ], w[k  ], a0);
    a1 = fmaf(r[k+1], w[k+1], a1);
    a2 = fmaf(r[k+2], w[k+2], a2);
    a3 = fmaf(r[k+3], w[k+3], a3);
  }
  return (a0+a1)+(a2+a3);
}
__device__ __forceinline__ v2f dotp16s(const float* r, const v2f* w, v2f init){
  v2f a0 = __builtin_elementwise_fma((v2f){r[0],r[0]}, w[0], init);
  v2f a1 = (v2f){r[1],r[1]}*w[1];
  v2f a2 = (v2f){r[2],r[2]}*w[2];
  v2f a3 = (v2f){r[3],r[3]}*w[3];
  #pragma unroll
  for (int k=4;k<16;k+=4){
    a0 = __builtin_elementwise_fma((v2f){r[k  ],r[k  ]}, w[k  ], a0);
    a1 = __builtin_elementwise_fma((v2f){r[k+1],r[k+1]}, w[k+1], a1);
    a2 = __builtin_elementwise_fma((v2f){r[k+2],r[k+2]}, w[k+2], a2);
    a3 = __builtin_elementwise_fma((v2f){r[k+3],r[k+3]}, w[k+3], a3);
  }
  return (a0+a1)+(a2+a3);
}

template<int NROW, int NCOL>
__device__ __forceinline__ void loadrot(float* dst, const float* W, int j, int col,
                                        bool colok, float scale){
  int colc = colok ? col : 0;
  #pragma unroll
  for (int k=0;k<16;k++){
    int i = (j - k) & 15;
    bool v = colok && (i < NROW);
    int ic = v ? i : 0;
    float w = W[ic*NCOL + colc];
    dst[k] = v ? scale*w : 0.f;
  }
}
__device__ __forceinline__ float bload(const float* p, int idx, bool ok, float scale){
  float t = p[ok ? idx : 0];
  return ok ? scale*t : 0.f;
}
template<int X> __device__ __forceinline__ float xor16(float x){
  return __int_as_float(__builtin_amdgcn_ds_swizzle(__float_as_int(x), (X<<10)|0x1f));
}
__device__ __forceinline__ int imin255(int t){ return t > 255 ? 255 : t; }

struct P34 { const float* p[34]; float* out; };

// r12 roles (best measured), superstep cadence: ONE barrier per 2 steps.
// wave0: serial chain + transition-prior + KLD      (z -> 4-slot LDS ring)
// wave1: e-stage (ae -> 4-slot ring) + generator + GLL + stores
// Superstep k: wave0 runs s=2k+1,2k+2 (reads ae slots (2k+1)&3,(2k+2)&3, writes z same
// slots); wave1 writes ae(2k+3),(2k+4) and reads z(2k-1),(2k) — all 4 slots distinct.
__global__ __attribute__((amdgpu_flat_work_group_size(128, 128), amdgpu_waves_per_eu(1, 1)))
void k_fused(P34 prm)
{
  __shared__ float s_ae[4][64];
  __shared__ float s_z [4][64];
  __shared__ float part[2][4];

  const int tx   = threadIdx.x;
  const int wid  = tx >> 6;
  const int lane = tx & 63;
  const int j    = lane & 15;
  const int grp  = lane >> 4;
  const int b    = blockIdx.x*4 + grp;
  const bool act = (j < HID);
  const int  jl  = act ? j : 0;

  const float* __restrict__ seq   = prm.p[0];
  const float* __restrict__ noise = prm.p[1];
  float* __restrict__ out = prm.out;

  float LL = 0.f, L2 = 0.f;

  if (wid == 0){
    // =============== wave 0: chain + prior + KLD ===============
    float w_jz[16]; loadrot<10,10>(w_jz, prm.p[12] + 100, j, j, act, S2P);
    float w_h [16]; loadrot<10,10>(w_h,  prm.p[14],       j, j, act, S2P);
    float tmu [16]; loadrot<10,10>(tmu,  prm.p[16],       j, j, act, S2P);
    float tsg [16]; loadrot<10,10>(tsg,  prm.p[18],       j, j, act, SNP);
    v2f wmsg[16];
    #pragma unroll
    for (int k=0;k<16;k++) wmsg[k] = (v2f){tmu[k], tsg[k]};
    float b_in_h  = bload(prm.p[15], jl, act, S2P);
    const v2f bmsg = (v2f){bload(prm.p[17], jl, act, S2P), bload(prm.p[19], jl, act, SNP)};
    float wth [16]; loadrot<10,10>(wth,  prm.p[20], j, j, act, S2P);
    float bth  = bload(prm.p[21], jl, act, S2P);
    float ttmu[16]; loadrot<10,10>(ttmu, prm.p[22], j, j, act, S2P);
    float ttsg[16]; loadrot<10,10>(ttsg, prm.p[24], j, j, act, S2P);
    v2f wpr[16];
    #pragma unroll
    for (int k=0;k<16;k++) wpr[k] = (v2f){ttmu[k], ttsg[k]};
    const v2f bpr = (v2f){bload(prm.p[23], jl, act, S2P), bload(prm.p[25], jl, act, S2P)};

    auto lde = [&](int t){ return noise[t*BATCH*HID + b*HID + jl]; };

    float z_prev;
    { // t=0: first_inference + KL vs unit prior
      float w0 = bload(prm.p[2],      jl, act, S2P);
      float w1 = bload(prm.p[2], 10 + jl, act, S2P);
      float bb = bload(prm.p[3], jl, act, S2P);
      float f_h[16], f_mu[16], f_sg[16];
      loadrot<10,10>(f_h,  prm.p[4], j, j, act, S2P);  float fb_h  = bload(prm.p[5], jl, act, S2P);
      loadrot<10,10>(f_mu, prm.p[6], j, j, act, S2P);  float fb_mu = bload(prm.p[7], jl, act, S2P);
      loadrot<10,10>(f_sg, prm.p[8], j, j, act, SNP);  float fb_sg = bload(prm.p[9], jl, act, SNP);
      float2 x0 = *reinterpret_cast<const float2*>(seq + b*2);
      float eps = lde(0);
      float h0 = ftanh2(fmaf(x0.x, w0, fmaf(x0.y, w1, bb)));
      float r0[16]; ROT16(r0, h0);
      float h1 = ftanh2(dot16(r0, f_h, fb_h));
      float r1[16]; ROT16(r1, h1);
      float mu = ftanh2(dot16(r1, f_mu, fb_mu));
      float sg = fsigm2(dot16(r1, f_sg, fb_sg)) + 0.001f;
      if (act){ LL += sg + mu*mu; L2 -= __log2f(sg); }
      z_prev = fmaf(sg, eps, mu);
      s_z[0][lane] = z_prev;
    }
    float e0=lde(1), e1=lde(2), e2=lde(3), e3=lde(4);
    __syncthreads();                                   // prologue barrier

    auto w0step = [&](int sl, float ec){
      float aev = s_ae[sl][lane];
      float rz[16]; ROT16(rz, z_prev);
      float hj = ftanh2(aev + dot16(rz, w_jz, 0.f));
      float rhj[16]; ROT16(rhj, hj);
      float hi = ftanh2(dot16(rhj, w_h, b_in_h));
      float rhi[16]; ROT16(rhi, hi);
      v2f d2 = dotp16s(rhi, wmsg, bmsg);
      float q_mu = ftanh2(d2.x);
      float q_sg = fsigm2(d2.y) + 0.001f;
      float z = fmaf(q_sg, ec, q_mu);
      s_z[sl][lane] = z;
      // prior + KLD off rz (independent of chain -> fills stalls)
      float th = ftanh2(dot16(rz, wth, bth));
      float rth[16]; ROT16(rth, th);
      v2f d3 = dotp16s(rth, wpr, bpr);
      float prmu = ftanh2(d3.x);
      float prsg = ftanh2(d3.y);
      if (act){
        float dmu = prmu - q_mu;
        float rp  = frcp(prsg);
        LL += (q_sg + dmu*dmu)*rp;
        L2 += __log2f(prsg) - __log2f(q_sg);
      }
      z_prev = z;
    };

    for (int k = 0; k < 128; ++k){
      int s0 = 2*k + 1, s1 = s0 + 1;
      float n0 = lde(imin255(s0+4)), n1 = lde(imin255(s0+5));
      int sl0 = s0 & 3;
      w0step(sl0, e0);
      if (s1 <= 255) w0step((sl0+1)&3, e1);            // skipped only at k=127
      e0=e2; e1=e3; e2=n0; e3=n1;
      __syncthreads();
    }
  } else {
    // =============== wave 1: e-stage + generator + GLL ===============
    float w_ii0   = bload(prm.p[10],      jl, act, S2P);
    float w_ii1   = bload(prm.p[10], 10 + jl, act, S2P);
    float b_in_in = bload(prm.p[11], jl, act, S2P);
    float w_je[16]; loadrot<10,10>(w_je, prm.p[12], j, j, act, S2P);
    float b_in_j  = bload(prm.p[13], jl, act, S2P);

    float wg1[16]; loadrot<10,10>(wg1, prm.p[26], j, j, act, 1.f);
    float bg1 = bload(prm.p[27], jl, act, 1.f);
    float wg2[16]; loadrot<10,10>(wg2, prm.p[28], j, j, act, 1.f);
    float bg2 = bload(prm.p[29], jl, act, 1.f);
    const bool isd = (j < 4);
    const float* Wgo = (j < 2) ? prm.p[30] : prm.p[32];
    const float* Bgo = (j < 2) ? prm.p[31] : prm.p[33];
    float wgo[16]; loadrot<10,2>(wgo, Wgo, j, j & 1, isd, SNP);
    float bgo = bload(Bgo, j & 1, isd, SNP);

    auto ldx = [&](int t){ return *reinterpret_cast<const float2*>(seq + t*BATCH*2 + b*2); };

    auto estage = [&](float2 xe, int sl){
      float e = ftanh2(fmaf(xe.x, w_ii0, fmaf(xe.y, w_ii1, b_in_in)));
      float re[16]; ROT16(re, e);
      s_ae[sl][lane] = dot16(re, w_je, b_in_j);
    };
    auto genstep = [&](int sl, int tG, float2 xg){
      float zl = s_z[sl][lane];
      float rz[16]; ROT16(rz, zl);
      float g1 = fmaxf(dot16(rz, wg1, bg1), 0.f);
      float rg1[16]; ROT16(rg1, g1);
      float g2 = fmaxf(dot16(rg1, wg2, bg2), 0.f);
      float rg2[16]; ROT16(rg2, g2);
      float ygo = dot16(rg2, wgo, bgo);
      float tgo = 1.f + ex2(ygo);                      // 1/sigmoid
      float tpl = rotk<14>(tgo);                       // lanes 0,1 <- 2,3
      if (j < 2){
        float m = frcp(tgo);
        out[tG*(BATCH*2) + b*2 + j] = m;
        float dd = ((j==0) ? xg.x : xg.y) - m;
        LL -= dd*dd*tpl;
        L2 += __log2f(tpl);
      }
    };

    // prologue: ae(1), ae(2); x-queue invariant at superstep k:
    // xA=x(2k-1) xB=x(2k) xC=x(2k+1) xD=x(2k+2) xe0=x(2k+3) xe1=x(2k+4)
    float2 x1 = ldx(1), x2 = ldx(2);
    estage(x1, 1); estage(x2, 2);
    float2 xB = ldx(0), xC = x1, xD = x2, xe0 = ldx(3), xe1 = ldx(4);
    float2 xA = xB;                                    // dummy at k=0
    __syncthreads();                                   // prologue barrier

    for (int k = 0; k < 128; ++k){
      int t0 = 2*k + 3, t1 = t0 + 1;
      float2 xen0 = ldx(imin255(t0+2)), xen1 = ldx(imin255(t0+3));
      if (t0 <= 255) estage(xe0, t0 & 3);
      if (t1 <= 255) estage(xe1, t1 & 3);
      int tg = 2*k;
      if (k >= 1) genstep((tg-1) & 3, tg-1, xA);
      genstep(tg & 3, tg, xB);                         // tg <= 254
      xA=xC; xB=xD; xC=xe0; xD=xe1; xe0=xen0; xe1=xen1;
      __syncthreads();
    }
    genstep(3, 255, xA);                               // xA = x(255); z(255) in slot 3
  }

  // combine per-wave loss partials
  float tot = fmaf(LN2, L2, LL);
  tot += xor16<1>(tot); tot += xor16<2>(tot); tot += xor16<4>(tot); tot += xor16<8>(tot);
  if (j == 0) part[wid][grp] = tot;
  __syncthreads();
  if (wid == 0 && j == 0)
    out[T_STEPS*BATCH*2 + b] =
      -(part[0][grp] + part[1][grp])*(1.0f/512.0f) + 5.0f + LOGPI;
}

extern "C" void kernel_launch(void* const* d_in, const int* in_sizes, int n_in,
                              void* d_out, int out_size, void* d_ws, size_t ws_size,
                              hipStream_t stream) {
  P34 prm;
  for (int i = 0; i < 34; ++i) prm.p[i] = (const float*)d_in[i];
  prm.out = (float*)d_out;
  hipLaunchKernelGGL(k_fused, dim3(512), dim3(128), 0, stream, prm);
}